// Round 7
// baseline (95.304 us; speedup 1.0000x reference)
//
#include <hip/hip_runtime.h>
#include <hip/hip_bf16.h>

// ConvMosaic via bf16 MFMA, barrier-free main kernel.
// y[n,co,h,w] = sum_{c,di,dj} x[n,c,h+di-1,w+dj-1] * W[w%16, c*9+di*3+dj, co]
// v7: pre-pass builds zero-padded NHWC bf16 tensor xb[4][258][258][32] so the
//     main kernel is pure {global A/B loads -> MFMA -> store}: no LDS, no
//     __syncthreads (rounds 4-6 showed barrier phase-alignment pinned us at
//     ~60us regardless of schedule). A-fragments are 16B contiguous in c.

using bf16 = __hip_bfloat16;
typedef __attribute__((ext_vector_type(8))) short bf16x8_t;  // A/B frag: 8 bf16 (4 VGPR)
typedef __attribute__((ext_vector_type(4))) float f32x4_t;   // C/D frag

constexpr int NB    = 4;
constexpr int C_IN  = 32;
constexpr int HH    = 256;
constexpr int WW    = 256;
constexpr int C_OUT = 64;
constexpr int SPE   = 16;

constexpr int HP = HH + 2;   // 258 padded
constexpr int WP = WW + 2;   // 258 padded

// ---- pre-pass 1: W[s][c*9+tap][co] f32 -> W_t[s][co][tap*32+c] bf16 ----
__global__ __launch_bounds__(256)
void prep_weights(const float* __restrict__ w, bf16* __restrict__ wt) {
    int idx = blockIdx.x * 256 + threadIdx.x;  // 16*64*288 total
    if (idx >= SPE * C_OUT * 288) return;
    int s  = idx / (C_OUT * 288);
    int r  = idx % (C_OUT * 288);
    int co = r / 288;
    int kk = r % 288;            // kk = tap*32 + c
    int tap = kk >> 5;
    int c   = kk & 31;
    float v = w[((size_t)s * 288 + c * 9 + tap) * C_OUT + co];
    wt[idx] = __float2bfloat16(v);
}

// ---- pre-pass 2: x[n][c][h][w] f32 -> xb[n][h+1][w+1][c] bf16, halo = 0 ----
__global__ __launch_bounds__(256)
void prep_x(const float* __restrict__ x, bf16* __restrict__ xb) {
    const int hp = blockIdx.x;          // 0..257
    const int n  = blockIdx.y;
    const int t  = threadIdx.x;
    const int wl = t & 63;              // w lane
    const int c0 = (t >> 6) * 8;        // channel group of 8

    const float* xn = x + (size_t)n * C_IN * HH * WW;
    bf16* xr = xb + (((size_t)n * HP + hp) * WP) * C_IN;

#pragma unroll
    for (int it = 0; it < 5; ++it) {
        const int wp = wl + it * 64;
        if (wp < WP) {
            const bool inb = (hp >= 1) && (hp <= HH) && (wp >= 1) && (wp <= WW);
            union { bf16x8_t v; bf16 e[8]; } u;
#pragma unroll
            for (int j = 0; j < 8; ++j) {
                float vv = 0.0f;
                if (inb)
                    vv = xn[((size_t)(c0 + j) * HH + (hp - 1)) * WW + (wp - 1)];
                u.e[j] = __float2bfloat16(vv);
            }
            *reinterpret_cast<bf16x8_t*>(&xr[(size_t)wp * C_IN + c0]) = u.v;
        }
    }
}

// ---- main: barrier-free, LDS-free MFMA conv ----
__global__ __launch_bounds__(1024, 4)
void conv_mosaic_mfma(const bf16* __restrict__ xb,
                      const bf16* __restrict__ wt,
                      float* __restrict__ out) {
    const int n  = blockIdx.y;
    const int tw = blockIdx.x & 7;    // 8 w-tiles of 32
    const int th = blockIdx.x >> 3;   // 16 h-tiles of 16
    const int h0 = th * 16;
    const int w0 = tw * 32;
    const int t  = threadIdx.x;

    // 16 waves: wave = s-group (wave&3) x c_out tile (wave>>2)
    const int wave = t >> 6;
    const int lane = t & 63;
    const int g    = wave & 3;    // s = g*4 + si
    const int ct   = wave >> 2;   // co tile: co = ct*16 + lm
    const int lm   = lane & 15;   // A: row m (h). B/D: col n (co).
    const int lg   = lane >> 4;   // k-group; D row group

    // A base: xb[n][h0+lm+di][w0+g*4+si+wm*16+dj][lg*8]
    const bf16* an = xb + (((size_t)n * HP + h0 + lm) * WP + (w0 + g * 4)) * C_IN + lg * 8;
    // B base: wt[(s*64 + ct*16+lm)*288 + lg*8], s = g*4+si
    const bf16* bpb = wt + ((size_t)(g * 4 * C_OUT + ct * 16 + lm) * 288 + lg * 8);

    f32x4_t dacc[2][4];
#pragma unroll
    for (int b = 0; b < 2; ++b)
#pragma unroll
        for (int c = 0; c < 4; ++c) dacc[b][c] = (f32x4_t){0.f, 0.f, 0.f, 0.f};

#pragma unroll
    for (int si = 0; si < 4; ++si) {
        // 9 B fragments for this si
        bf16x8_t bfr[9];
#pragma unroll
        for (int tap = 0; tap < 9; ++tap)
            bfr[tap] = *reinterpret_cast<const bf16x8_t*>(
                bpb + (size_t)si * C_OUT * 288 + tap * 32);

#pragma unroll
        for (int tap = 0; tap < 9; ++tap) {
            const int di = tap / 3, dj = tap % 3;
            bf16x8_t a0 = *reinterpret_cast<const bf16x8_t*>(
                an + (di * WP + si + dj) * C_IN);
            bf16x8_t a1 = *reinterpret_cast<const bf16x8_t*>(
                an + (di * WP + si + dj + 16) * C_IN);
            dacc[0][si] = __builtin_amdgcn_mfma_f32_16x16x32_bf16(a0, bfr[tap], dacc[0][si], 0, 0, 0);
            dacc[1][si] = __builtin_amdgcn_mfma_f32_16x16x32_bf16(a1, bfr[tap], dacc[1][si], 0, 0, 0);
        }
    }

    // ---- store: float4 across si (4 consecutive w) ----
    const int co = ct * 16 + lm;
#pragma unroll
    for (int wm = 0; wm < 2; ++wm) {
#pragma unroll
        for (int j = 0; j < 4; ++j) {
            const int h = h0 + lg * 4 + j;
            float4 v = make_float4(dacc[wm][0][j], dacc[wm][1][j],
                                   dacc[wm][2][j], dacc[wm][3][j]);
            *reinterpret_cast<float4*>(
                &out[(((size_t)n * C_OUT + co) * HH + h) * WW + w0 + g * 4 + wm * 16]) = v;
        }
    }
}

extern "C" void kernel_launch(void* const* d_in, const int* in_sizes, int n_in,
                              void* d_out, int out_size, void* d_ws, size_t ws_size,
                              hipStream_t stream) {
    const float* x = (const float*)d_in[0];
    const float* w = (const float*)d_in[1];
    float* out     = (float*)d_out;

    // d_ws layout: [0, 589824) = wt ; [1MiB, 1MiB+17040384) = xb
    bf16* wt = (bf16*)d_ws;
    bf16* xb = (bf16*)((char*)d_ws + (1u << 20));

    prep_weights<<<(SPE * C_OUT * 288 + 255) / 256, 256, 0, stream>>>(w, wt);
    prep_x<<<dim3(HP, NB), 256, 0, stream>>>(x, xb);

    dim3 grid((WW / 32) * (HH / 16), NB);  // (8*16, 4) = 512 blocks
    conv_mosaic_mfma<<<grid, 1024, 0, stream>>>(xb, wt, out);
}

// Round 10
// 67.606 us; speedup vs baseline: 1.4097x; 1.4097x over previous
//
#include <hip/hip_runtime.h>
#include <hip/hip_bf16.h>

// ConvMosaic via bf16 MFMA 32x32x16 (LDS-staged, plain HIP loads).
// y[n,co,h,w] = sum_{c,di,dj} x[n,c,h+di-1,w+dj-1] * W[w%16, c*9+di*3+dj, co]
// v10: switch 16x16x32 -> 32x32x16. Rationale (r4-r7 counters): structure was
//   LDS-pipe + transaction bound, not BW bound. 32x32 halves ds_read_b128 and
//   MFMA-issue cycles per output, and the repacked weight layout makes every
//   B-load a contiguous 1KB wave access (4 transactions vs 16).
//   Tile 32h x 16w, 8 waves = (s-group g) x (co-half ct2). Verified D layout:
//   col=lane&31 (co), row=(reg&3)+8*(reg>>2)+4*(lane>>5) (h). A/B: row/col =
//   lane&31, k = 8*(lane>>5)+v.

using bf16 = __hip_bfloat16;
typedef __attribute__((ext_vector_type(8))) short bf16x8_t;    // A/B frag: 8 bf16
typedef __attribute__((ext_vector_type(16))) float f32x16_t;   // C/D frag: 16 f32

constexpr int NB    = 4;
constexpr int C_IN  = 32;
constexpr int HH    = 256;
constexpr int WW    = 256;
constexpr int C_OUT = 64;
constexpr int SPE   = 16;

constexpr int TH  = 32;         // tile height (== MFMA M)
constexpr int TW  = 16;         // tile width (one full s period)
constexpr int XR  = TH + 2;     // 34 rows
constexpr int XC  = TW + 2;     // 18 real cols
constexpr int XCL = 19;         // col slots (row stride 19*40 els = 380 dw = 28 mod 32)
constexpr int CPAD = 40;        // c-dim padded 32->40 els (80 B col stride, 16B-aligned)

// ---- pre-pass: W[s][c*9+tap][co] -> wt3 packed per-fragment lane order ----
// flat idx = ((((s*2+ct2)*9+tap)*2+kh)*64 + lane)*8 + v
// element  = W[s][ (kh*16 + (lane>>5)*8 + v)*9 + tap ][ ct2*32 + (lane&31) ]
// => each (s,ct2,tap,kh) fragment is a contiguous 1KB block read coalesced.
__global__ __launch_bounds__(256)
void prep_weights(const float* __restrict__ w, bf16* __restrict__ wt3) {
    int o = blockIdx.x * 256 + threadIdx.x;
    if (o >= SPE * 2 * 9 * 2 * 64 * 8) return;   // 294912
    int v   = o & 7;
    int l   = (o >> 3) & 63;
    int kh  = (o >> 9) & 1;
    int r   = o >> 10;            // (s*2+ct2)*9 + tap
    int tap = r % 9;
    int sc  = r / 9;
    int ct2 = sc & 1;
    int s   = sc >> 1;
    int c   = kh * 16 + (l >> 5) * 8 + v;
    int co  = ct2 * 32 + (l & 31);
    wt3[o] = __float2bfloat16(w[((size_t)s * 288 + c * 9 + tap) * C_OUT + co]);
}

__global__ __launch_bounds__(512, 4)
void conv_mosaic_mfma(const float* __restrict__ x,
                      const bf16* __restrict__ wt3,
                      float* __restrict__ out) {
    __shared__ __align__(16) bf16 xs[XR * XCL * CPAD];  // 34*19*40*2 = 51680 B

    const int n  = blockIdx.y;
    const int tw = blockIdx.x & 15;   // 16 w-tiles
    const int th = blockIdx.x >> 4;   // 8 h-tiles
    const int h0 = th * TH;
    const int w0 = tw * TW;
    const int t  = threadIdx.x;

    // 8 waves: wave = s-group (wave&3) x co-half (wave>>2)
    const int wave = t >> 6;
    const int lane = t & 63;
    const int g    = wave & 3;    // s = g*4 + si
    const int ct2  = wave >> 2;   // co = ct2*32 + lr
    const int lr   = lane & 31;   // A row (h) / B col (co) / D col (co)
    const int lk   = lane >> 5;   // k sub-group: klocal = 8*lk + v

    // ---- stage x tile (zero-padded halo), f32 -> bf16, layout [row][col][c] ----
    const float* xn = x + (size_t)n * C_IN * HH * WW;
    constexpr int VJOBS = C_IN * XR * 4;  // 4352 (interior cols 1..16, float4 over w)
#pragma unroll
    for (int it = 0; it < 9; ++it) {
        const int idx = t + it * 512;
        if (idx < VJOBS) {
            const int c  = idx / (XR * 4);
            const int rr = idx % (XR * 4);
            const int r  = rr >> 2;
            const int q  = rr & 3;
            const int gh = h0 + r - 1;
            float4 v = make_float4(0.f, 0.f, 0.f, 0.f);
            if (gh >= 0 && gh < HH)
                v = *reinterpret_cast<const float4*>(
                    &xn[((size_t)c * HH + gh) * WW + w0 + q * 4]);
            bf16* d = &xs[(r * XCL + q * 4 + 1) * CPAD + c];
            d[0]        = __float2bfloat16(v.x);
            d[CPAD]     = __float2bfloat16(v.y);
            d[2 * CPAD] = __float2bfloat16(v.z);
            d[3 * CPAD] = __float2bfloat16(v.w);
        }
    }
    // halo edge cols 0 and 17 (scalar, bounds-checked in h and w)
    constexpr int EJOBS = C_IN * XR * 2;  // 2176
#pragma unroll
    for (int it = 0; it < 5; ++it) {
        const int idx = t + it * 512;
        if (idx < EJOBS) {
            const int c   = idx / (XR * 2);
            const int rr  = idx % (XR * 2);
            const int r   = rr >> 1;
            const int e   = rr & 1;
            const int col = e ? (XC - 1) : 0;
            const int gh  = h0 + r - 1;
            const int gw  = w0 + (e ? TW : -1);
            float vv = 0.f;
            if (gh >= 0 && gh < HH && gw >= 0 && gw < WW)
                vv = xn[((size_t)c * HH + gh) * WW + gw];
            xs[(r * XCL + col) * CPAD + c] = __float2bfloat16(vv);
        }
    }
    __syncthreads();

    // accumulators: one 32x32 tile per si (w column set)
    f32x16_t dacc[4];
#pragma unroll
    for (int si = 0; si < 4; ++si)
#pragma unroll
        for (int j = 0; j < 16; ++j) dacc[si][j] = 0.f;

#pragma unroll
    for (int si = 0; si < 4; ++si) {
        const int s = g * 4 + si;   // == local w column (w0 + s)
        // B fragment block base for (s, ct2): el offset (s*2+ct2)*9216 + lane*8
        const bf16* bp = wt3 + (size_t)(s * 2 + ct2) * 9216 + lane * 8;
        // A base: row lr(+di), col s(+dj), c-slice lk*8 (+kh*16)
        const bf16* ap = &xs[(lr * XCL + s) * CPAD + lk * 8];
#pragma unroll
        for (int kh = 0; kh < 2; ++kh) {
            bf16x8_t bfr[9];
#pragma unroll
            for (int tap = 0; tap < 9; ++tap)
                bfr[tap] = *reinterpret_cast<const bf16x8_t*>(bp + (tap * 2 + kh) * 512);
            __builtin_amdgcn_sched_barrier(0);
#pragma unroll
            for (int tap = 0; tap < 9; ++tap) {
                const int di = tap / 3, dj = tap % 3;
                bf16x8_t a = *reinterpret_cast<const bf16x8_t*>(
                    ap + (di * XCL + dj) * CPAD + kh * 16);
                dacc[si] = __builtin_amdgcn_mfma_f32_32x32x16_bf16(
                    a, bfr[tap], dacc[si], 0, 0, 0);
            }
        }
    }

    // ---- store: float4 across si (4 consecutive w at w0 + g*4) ----
    const int co = ct2 * 32 + lr;
#pragma unroll
    for (int j = 0; j < 16; ++j) {
        const int h = h0 + (j & 3) + 8 * (j >> 2) + 4 * lk;
        float4 v = make_float4(dacc[0][j], dacc[1][j], dacc[2][j], dacc[3][j]);
        *reinterpret_cast<float4*>(
            &out[(((size_t)n * C_OUT + co) * HH + h) * WW + w0 + g * 4]) = v;
    }
}

extern "C" void kernel_launch(void* const* d_in, const int* in_sizes, int n_in,
                              void* d_out, int out_size, void* d_ws, size_t ws_size,
                              hipStream_t stream) {
    const float* x = (const float*)d_in[0];
    const float* w = (const float*)d_in[1];
    float* out     = (float*)d_out;
    bf16* wt3      = (bf16*)d_ws;   // 294912*2 = 589824 B

    prep_weights<<<(SPE * 2 * 9 * 2 * 64 * 8 + 255) / 256, 256, 0, stream>>>(w, wt3);

    dim3 grid((WW / TW) * (HH / TH), NB);  // (16*8, 4) = 512 blocks
    conv_mosaic_mfma<<<grid, 512, 0, stream>>>(x, wt3, out);
}